// Round 14
// baseline (340.779 us; speedup 1.0000x reference)
//
#include <hip/hip_runtime.h>
#include <stdint.h>

#define N_NODES 50000
#define N_EDGES 800000
#define N_PAD   50176    // 98 * 512, K-padding for MFMA pool
#define PCHUNK  512
#define NCHUNKS 98
#define FEAT    128
#define NGRAPH  64

#define E_BLKS      3125   // 800000 edges / 256
#define GSTRIP_BLKS 782    // ceil(3125 row-strips / 4 waves)
#define GR_BLKS     (GSTRIP_BLKS + E_BLKS)   // interleaved 1:4
#define CZ_BLKS     3136   // 64*N_PAD*4B / (256 thr * 16B)
#define CP_BLKS     1563   // cnt_p zero: 400000 float4 / 256
#define Z2_F4       16416  // f_sum..Y4 (+ticket) zero: float4 count
#define Z2_BLKS     65
#define PREP_BLKS   (32 + CZ_BLKS + CP_BLKS + Z2_BLKS)
#define AGG_BLKS    12500  // N_NODES / 4 nodes per block

typedef __attribute__((ext_vector_type(8))) short short8;
typedef __attribute__((ext_vector_type(4))) float floatx4;

static __device__ __forceinline__ ushort f2bf(float f) {
  uint32_t x = __float_as_uint(f);
  x += 0x7FFF + ((x >> 16) & 1);   // RNE
  return (ushort)(x >> 16);
}
static __device__ __forceinline__ float bfLo(uint32_t u) {
  return __uint_as_float(u << 16);
}
static __device__ __forceinline__ float bfHi(uint32_t u) {
  return __uint_as_float(u & 0xFFFF0000u);
}

// cvt + transpose: in is row-major [128][128] fp32 [k][n], out is [n][k] bf16
static __device__ __forceinline__ void cvt4T(const float* __restrict__ in,
                                             ushort* __restrict__ outT, int i) {
  float4 v = ((const float4*)in)[i];
  int k = (4 * i) >> 7;          // row
  int n = (4 * i) & 127;         // col
  outT[(size_t)(n + 0) * FEAT + k] = f2bf(v.x);
  outT[(size_t)(n + 1) * FEAT + k] = f2bf(v.y);
  outT[(size_t)(n + 2) * FEAT + k] = f2bf(v.z);
  outT[(size_t)(n + 3) * FEAT + k] = f2bf(v.w);
}

// ---- prep: weight transpose-cvt + all workspace zeroing (memsets folded)
__global__ __launch_bounds__(256) void prep_fused(const float* __restrict__ w0,
                                                  const float* __restrict__ w1,
                                                  ushort* __restrict__ wbT,
                                                  float* __restrict__ coefT,
                                                  float4* __restrict__ zcnt,
                                                  float4* __restrict__ zfy) {
  int b = blockIdx.x, t = threadIdx.x;
  if (b < 32) {
    int i = b * 256 + t;                       // 0..8191
    if (i < 4096) cvt4T(w0, wbT, i);
    else cvt4T(w1, wbT + FEAT * FEAT, i - 4096);
  } else if (b < 32 + CZ_BLKS) {
    int i = (b - 32) * 256 + t;                // 0..802815 exactly
    ((float4*)coefT)[i] = make_float4(0.f, 0.f, 0.f, 0.f);
  } else if (b < 32 + CZ_BLKS + CP_BLKS) {
    int i = (b - 32 - CZ_BLKS) * 256 + t;      // cnt_p: 400000 float4
    if (i < 400000) zcnt[i] = make_float4(0.f, 0.f, 0.f, 0.f);
  } else {
    int i = (b - 32 - CZ_BLKS - CP_BLKS) * 256 + t;   // f_sum..Y4+ticket
    if (i < Z2_F4) zfy[i] = make_float4(0.f, 0.f, 0.f, 0.f);
  }
}

// ---- row-strip gemm, A from fp32 (in-reg cvt): wave owns 16x128 strip ---
static __device__ __forceinline__ void gemm_strip_f32a(int strip, int lane,
                                                       const float* __restrict__ X,
                                                       const ushort* __restrict__ WT,
                                                       ushort* __restrict__ XW) {
  if (strip >= N_NODES / 16) return;
  int m0 = strip * 16;
  int r = lane & 15, quad = lane >> 4;
  const float* xrow = X + (size_t)(m0 + r) * FEAT;
  short8 afr[4];
#pragma unroll
  for (int kb = 0; kb < 4; ++kb) {
    int k0 = kb * 32 + quad * 8;
    float4 f0 = *(const float4*)(xrow + k0);
    float4 f1 = *(const float4*)(xrow + k0 + 4);
    short8 a;
    a[0] = (short)f2bf(f0.x); a[1] = (short)f2bf(f0.y);
    a[2] = (short)f2bf(f0.z); a[3] = (short)f2bf(f0.w);
    a[4] = (short)f2bf(f1.x); a[5] = (short)f2bf(f1.y);
    a[6] = (short)f2bf(f1.z); a[7] = (short)f2bf(f1.w);
    afr[kb] = a;
  }
#pragma unroll
  for (int nt = 0; nt < 8; ++nt) {
    int n0 = nt * 16;
    floatx4 acc = {0.f, 0.f, 0.f, 0.f};
    const ushort* wrow = WT + (size_t)(n0 + r) * FEAT;
#pragma unroll
    for (int kb = 0; kb < 4; ++kb) {
      short8 b = *(const short8*)(wrow + kb * 32 + quad * 8);
      acc = __builtin_amdgcn_mfma_f32_16x16x32_bf16(afr[kb], b, acc, 0, 0, 0);
    }
#pragma unroll
    for (int reg = 0; reg < 4; ++reg)
      XW[(size_t)(m0 + quad * 4 + reg) * FEAT + n0 + r] = f2bf(acc[reg]);
  }
}

// ---- K1: conv1 gemm (row-strip) interleaved 1:4 with rank atomics -------
// cnt_p is 128B-padded (cnt_p[dst*32]): each counter owns a full line.
__global__ __launch_bounds__(256) void gemm_rank(const float* __restrict__ x,
                                                 const ushort* __restrict__ wbT,
                                                 ushort* __restrict__ msl,
                                                 const int* __restrict__ dst,
                                                 int* __restrict__ cnt_p,
                                                 int* __restrict__ rank) {
  int b = blockIdx.x, t = threadIdx.x;
  int fifth = b / 5;
  if (b - fifth * 5 == 0) {
    gemm_strip_f32a(fifth * 4 + (t >> 6), t & 63, x, wbT, msl);
  } else {
    int e = (b - fifth - 1) * 256 + t;         // 0..799999 exactly
    rank[e] = atomicAdd(&cnt_p[dst[e] * 32], 1);
  }
}

// ---- conv2 gemm: row-strip, A bf16 (loaded once, 8 n-tiles reuse) -------
__global__ __launch_bounds__(256) void gemm2_strip(const ushort* __restrict__ X,
                                                   const ushort* __restrict__ WT,
                                                   ushort* __restrict__ XW) {
  int strip = (blockIdx.x * 256 + threadIdx.x) >> 6;
  int lane = threadIdx.x & 63;
  if (strip >= N_NODES / 16) return;
  int m0 = strip * 16;
  int r = lane & 15, quad = lane >> 4;
  const ushort* xrow = X + (size_t)(m0 + r) * FEAT;
  short8 afr[4];
#pragma unroll
  for (int kb = 0; kb < 4; ++kb)
    afr[kb] = *(const short8*)(xrow + kb * 32 + quad * 8);
#pragma unroll
  for (int nt = 0; nt < 8; ++nt) {
    int n0 = nt * 16;
    floatx4 acc = {0.f, 0.f, 0.f, 0.f};
    const ushort* wrow = WT + (size_t)(n0 + r) * FEAT;
#pragma unroll
    for (int kb = 0; kb < 4; ++kb) {
      short8 b = *(const short8*)(wrow + kb * 32 + quad * 8);
      acc = __builtin_amdgcn_mfma_f32_16x16x32_bf16(afr[kb], b, acc, 0, 0, 0);
    }
#pragma unroll
    for (int reg = 0; reg < 4; ++reg)
      XW[(size_t)(m0 + quad * 4 + reg) * FEAT + n0 + r] = f2bf(acc[reg]);
  }
}

// ---- fused: dinv + coefT self-term + graph counts + scan1 + scan2 -------
// scan2 folded via last-block ticket: each block release-fences its bsums
// write, the 196th arrival acquire-fences and scans bsums in-LDS.
__global__ __launch_bounds__(256) void dinv_scan1(const int* __restrict__ cnt_p,
                                                  const int* __restrict__ batch,
                                                  float* __restrict__ dinv,
                                                  float* __restrict__ cnt_g,
                                                  int* __restrict__ ptr,
                                                  int* __restrict__ bsums,
                                                  float* __restrict__ coefT,
                                                  int* __restrict__ ticket) {
  __shared__ int tmp[256];
  __shared__ int bins[NGRAPH];
  __shared__ int lastFlag;
  if (threadIdx.x < NGRAPH) bins[threadIdx.x] = 0;
  int i = blockIdx.x * 256 + threadIdx.x;
  int v = (i < N_NODES) ? cnt_p[i * 32] : 0;
  tmp[threadIdx.x] = v;
  __syncthreads();
  for (int off = 1; off < 256; off <<= 1) {
    int t = (threadIdx.x >= off) ? tmp[threadIdx.x - off] : 0;
    __syncthreads();
    tmp[threadIdx.x] += t;
    __syncthreads();
  }
  if (i < N_NODES) ptr[i] = tmp[threadIdx.x] - v;           // block-local excl
  if (threadIdx.x == 255) {
    bsums[blockIdx.x] = tmp[255];
    __threadfence();                                         // release
    lastFlag = (atomicAdd(ticket, 1) == (int)gridDim.x - 1);
  }
  if (i < N_NODES) {
    float di = rsqrtf((float)v + 1.0f);
    dinv[i] = di;
    int g = batch[i];
    coefT[(size_t)g * N_PAD + i] = di * di;   // self term (coalesced: sorted)
    atomicAdd(&bins[g], 1);
  }
  __syncthreads();
  if (threadIdx.x < NGRAPH && bins[threadIdx.x] > 0)
    atomicAdd(&cnt_g[threadIdx.x], (float)bins[threadIdx.x]);
  __syncthreads();
  if (lastFlag) {                                            // last block: scan2
    __threadfence();                                         // acquire
    int b = (threadIdx.x < (int)gridDim.x) ? bsums[threadIdx.x] : 0;
    tmp[threadIdx.x] = b;
    __syncthreads();
    for (int off = 1; off < 256; off <<= 1) {
      int t = (threadIdx.x >= off) ? tmp[threadIdx.x - off] : 0;
      __syncthreads();
      tmp[threadIdx.x] += t;
      __syncthreads();
    }
    if (threadIdx.x < (int)gridDim.x) bsums[threadIdx.x] = tmp[threadIdx.x] - b;
  }
}

// ---- fill: atomic-free CSR scatter, payload {src, dinv[src]} ------------
__global__ __launch_bounds__(256) void fill_csr(const int* __restrict__ src,
                                                const int* __restrict__ dst,
                                                const int* __restrict__ rank,
                                                const int* __restrict__ ptr,
                                                const int* __restrict__ bsums,
                                                const float* __restrict__ dinv,
                                                int2* __restrict__ edges) {
  int e = blockIdx.x * 256 + threadIdx.x;
  if (e >= N_EDGES) return;
  int s = src[e];
  int d = dst[e];
  edges[ptr[d] + bsums[d >> 8] + rank[e]] = make_int2(s, __float_as_int(dinv[s]));
}

// ---- edge-gather accumulator (16/8/4/2/1-edge ILP) ----------------------
static __device__ __forceinline__ float2 agg_node(const uint32_t* __restrict__ m32,
                                                  const int2* __restrict__ edges,
                                                  int start, int n, int lane) {
  float ax0 = 0.f, ay0 = 0.f, ax1 = 0.f, ay1 = 0.f;
  float ax2 = 0.f, ay2 = 0.f, ax3 = 0.f, ay3 = 0.f;
  int i = 0;
  if ((start & 1) && n > 0) {                   // align to int4 (2-edge) bound
    int2 e = edges[start];
    uint32_t u = m32[(size_t)e.x * 64 + lane];
    float nrm = __int_as_float(e.y);
    ax0 = fmaf(nrm, bfLo(u), ax0);
    ay0 = fmaf(nrm, bfHi(u), ay0);
    i = 1;
  }
  for (; i + 16 <= n; i += 16) {
    const int4* ep = (const int4*)(edges + start + i);   // 16B-aligned
    int4 q0 = ep[0], q1 = ep[1], q2 = ep[2], q3 = ep[3];
    int4 q4 = ep[4], q5 = ep[5], q6 = ep[6], q7 = ep[7];
    uint32_t u0 = m32[(size_t)q0.x * 64 + lane];
    uint32_t u1 = m32[(size_t)q0.z * 64 + lane];
    uint32_t u2 = m32[(size_t)q1.x * 64 + lane];
    uint32_t u3 = m32[(size_t)q1.z * 64 + lane];
    uint32_t u4 = m32[(size_t)q2.x * 64 + lane];
    uint32_t u5 = m32[(size_t)q2.z * 64 + lane];
    uint32_t u6 = m32[(size_t)q3.x * 64 + lane];
    uint32_t u7 = m32[(size_t)q3.z * 64 + lane];
    uint32_t u8 = m32[(size_t)q4.x * 64 + lane];
    uint32_t u9 = m32[(size_t)q4.z * 64 + lane];
    uint32_t uA = m32[(size_t)q5.x * 64 + lane];
    uint32_t uB = m32[(size_t)q5.z * 64 + lane];
    uint32_t uC = m32[(size_t)q6.x * 64 + lane];
    uint32_t uD = m32[(size_t)q6.z * 64 + lane];
    uint32_t uE = m32[(size_t)q7.x * 64 + lane];
    uint32_t uF = m32[(size_t)q7.z * 64 + lane];
    float n0 = __int_as_float(q0.y), n1 = __int_as_float(q0.w);
    float n2 = __int_as_float(q1.y), n3 = __int_as_float(q1.w);
    float n4 = __int_as_float(q2.y), n5 = __int_as_float(q2.w);
    float n6 = __int_as_float(q3.y), n7 = __int_as_float(q3.w);
    float n8 = __int_as_float(q4.y), n9 = __int_as_float(q4.w);
    float nA = __int_as_float(q5.y), nB = __int_as_float(q5.w);
    float nC = __int_as_float(q6.y), nD = __int_as_float(q6.w);
    float nE = __int_as_float(q7.y), nF = __int_as_float(q7.w);
    ax0 = fmaf(n0, bfLo(u0), ax0); ay0 = fmaf(n0, bfHi(u0), ay0);
    ax1 = fmaf(n1, bfLo(u1), ax1); ay1 = fmaf(n1, bfHi(u1), ay1);
    ax2 = fmaf(n2, bfLo(u2), ax2); ay2 = fmaf(n2, bfHi(u2), ay2);
    ax3 = fmaf(n3, bfLo(u3), ax3); ay3 = fmaf(n3, bfHi(u3), ay3);
    ax0 = fmaf(n4, bfLo(u4), ax0); ay0 = fmaf(n4, bfHi(u4), ay0);
    ax1 = fmaf(n5, bfLo(u5), ax1); ay1 = fmaf(n5, bfHi(u5), ay1);
    ax2 = fmaf(n6, bfLo(u6), ax2); ay2 = fmaf(n6, bfHi(u6), ay2);
    ax3 = fmaf(n7, bfLo(u7), ax3); ay3 = fmaf(n7, bfHi(u7), ay3);
    ax0 = fmaf(n8, bfLo(u8), ax0); ay0 = fmaf(n8, bfHi(u8), ay0);
    ax1 = fmaf(n9, bfLo(u9), ax1); ay1 = fmaf(n9, bfHi(u9), ay1);
    ax2 = fmaf(nA, bfLo(uA), ax2); ay2 = fmaf(nA, bfHi(uA), ay2);
    ax3 = fmaf(nB, bfLo(uB), ax3); ay3 = fmaf(nB, bfHi(uB), ay3);
    ax0 = fmaf(nC, bfLo(uC), ax0); ay0 = fmaf(nC, bfHi(uC), ay0);
    ax1 = fmaf(nD, bfLo(uD), ax1); ay1 = fmaf(nD, bfHi(uD), ay1);
    ax2 = fmaf(nE, bfLo(uE), ax2); ay2 = fmaf(nE, bfHi(uE), ay2);
    ax3 = fmaf(nF, bfLo(uF), ax3); ay3 = fmaf(nF, bfHi(uF), ay3);
  }
  if (i + 8 <= n) {
    const int4* ep = (const int4*)(edges + start + i);
    int4 q0 = ep[0], q1 = ep[1], q2 = ep[2], q3 = ep[3];
    uint32_t u0 = m32[(size_t)q0.x * 64 + lane];
    uint32_t u1 = m32[(size_t)q0.z * 64 + lane];
    uint32_t u2 = m32[(size_t)q1.x * 64 + lane];
    uint32_t u3 = m32[(size_t)q1.z * 64 + lane];
    uint32_t u4 = m32[(size_t)q2.x * 64 + lane];
    uint32_t u5 = m32[(size_t)q2.z * 64 + lane];
    uint32_t u6 = m32[(size_t)q3.x * 64 + lane];
    uint32_t u7 = m32[(size_t)q3.z * 64 + lane];
    float n0 = __int_as_float(q0.y), n1 = __int_as_float(q0.w);
    float n2 = __int_as_float(q1.y), n3 = __int_as_float(q1.w);
    float n4 = __int_as_float(q2.y), n5 = __int_as_float(q2.w);
    float n6 = __int_as_float(q3.y), n7 = __int_as_float(q3.w);
    ax0 = fmaf(n0, bfLo(u0), ax0); ay0 = fmaf(n0, bfHi(u0), ay0);
    ax1 = fmaf(n1, bfLo(u1), ax1); ay1 = fmaf(n1, bfHi(u1), ay1);
    ax2 = fmaf(n2, bfLo(u2), ax2); ay2 = fmaf(n2, bfHi(u2), ay2);
    ax3 = fmaf(n3, bfLo(u3), ax3); ay3 = fmaf(n3, bfHi(u3), ay3);
    ax0 = fmaf(n4, bfLo(u4), ax0); ay0 = fmaf(n4, bfHi(u4), ay0);
    ax1 = fmaf(n5, bfLo(u5), ax1); ay1 = fmaf(n5, bfHi(u5), ay1);
    ax2 = fmaf(n6, bfLo(u6), ax2); ay2 = fmaf(n6, bfHi(u6), ay2);
    ax3 = fmaf(n7, bfLo(u7), ax3); ay3 = fmaf(n7, bfHi(u7), ay3);
    i += 8;
  }
  if (i + 4 <= n) {                             // 4-edge mid tail
    const int4* ep = (const int4*)(edges + start + i);
    int4 q0 = ep[0], q1 = ep[1];
    uint32_t u0 = m32[(size_t)q0.x * 64 + lane];
    uint32_t u1 = m32[(size_t)q0.z * 64 + lane];
    uint32_t u2 = m32[(size_t)q1.x * 64 + lane];
    uint32_t u3 = m32[(size_t)q1.z * 64 + lane];
    float n0 = __int_as_float(q0.y), n1 = __int_as_float(q0.w);
    float n2 = __int_as_float(q1.y), n3 = __int_as_float(q1.w);
    ax0 = fmaf(n0, bfLo(u0), ax0); ay0 = fmaf(n0, bfHi(u0), ay0);
    ax1 = fmaf(n1, bfLo(u1), ax1); ay1 = fmaf(n1, bfHi(u1), ay1);
    ax2 = fmaf(n2, bfLo(u2), ax2); ay2 = fmaf(n2, bfHi(u2), ay2);
    ax3 = fmaf(n3, bfLo(u3), ax3); ay3 = fmaf(n3, bfHi(u3), ay3);
    i += 4;
  }
  if (i + 2 <= n) {                             // 2-edge tail
    const int4* ep = (const int4*)(edges + start + i);
    int4 q0 = ep[0];
    uint32_t u0 = m32[(size_t)q0.x * 64 + lane];
    uint32_t u1 = m32[(size_t)q0.z * 64 + lane];
    float n0 = __int_as_float(q0.y), n1 = __int_as_float(q0.w);
    ax0 = fmaf(n0, bfLo(u0), ax0); ay0 = fmaf(n0, bfHi(u0), ay0);
    ax1 = fmaf(n1, bfLo(u1), ax1); ay1 = fmaf(n1, bfHi(u1), ay1);
    i += 2;
  }
  for (; i < n; ++i) {
    int2 e = edges[start + i];
    float nrm = __int_as_float(e.y);
    uint32_t u = m32[(size_t)e.x * 64 + lane];
    ax0 = fmaf(nrm, bfLo(u), ax0);
    ay0 = fmaf(nrm, bfHi(u), ay0);
  }
  return make_float2((ax0 + ax1) + (ax2 + ax3), (ay0 + ay1) + (ay2 + ay3));
}

// ---- agg pass (1 wave/node). DO_COEF: fold coefT edge atomics into the
// walk — wave v updates ONLY row batch[v] (200KB window, batch-sorted
// neighbors -> L2-local RMW instead of random-12.8MB thrash), reusing the
// L1-hot edge list. Fire-and-forget, lanes parallel over edges. ----------
template <int DO_COEF>
__global__ __launch_bounds__(256) void agg_pass(const ushort* __restrict__ msg,
                                                const float* __restrict__ dinv,
                                                const int* __restrict__ ptr,
                                                const int* __restrict__ bsums,
                                                const int* __restrict__ cnt_p,
                                                const int2* __restrict__ edges,
                                                const float* __restrict__ bias,
                                                ushort* __restrict__ outp,
                                                const int* __restrict__ batch,
                                                float* __restrict__ coefT) {
  int wave = (blockIdx.x * 256 + threadIdx.x) >> 6;
  int lane = threadIdx.x & 63;
  if (wave >= N_NODES) return;
  int v = wave;
  float di = dinv[v];
  const uint32_t* m32 = (const uint32_t*)msg;
  uint32_t su = m32[(size_t)v * 64 + lane];
  int start = ptr[v] + bsums[v >> 8];
  int n = cnt_p[v * 32];
  float2 s = agg_node(m32, edges, start, n, lane);
  if (DO_COEF) {
    size_t grow = (size_t)batch[v] * N_PAD;
    for (int j = lane; j < n; j += 64) {
      int2 e = edges[start + j];
      atomicAdd(&coefT[grow + e.x], __int_as_float(e.y) * di);
    }
  }
  float ax = fmaf(fmaf(di, bfLo(su), s.x), di, bias[2 * lane]);
  float ay = fmaf(fmaf(di, bfHi(su), s.y), di, bias[2 * lane + 1]);
  ushort2 h2;
  h2.x = f2bf(fmaxf(ax, 0.f));
  h2.y = f2bf(fmaxf(ay, 0.f));
  ((ushort2*)outp)[(size_t)v * 64 + lane] = h2;
}

// ---- pool v2: P = coefT x h2 via MFMA, coefT staged to LDS (bf16) -------
__global__ __launch_bounds__(512) void pool_mfma(const ushort* __restrict__ h2,
                                                 const float* __restrict__ coefT,
                                                 float* __restrict__ P) {
  __shared__ ushort cs[64 * PCHUNK];             // 64 KB
  int t = threadIdx.x;
  int lane = t & 63;
  int w = t >> 6;                                // wave = n-tile 0..7
  int r = lane & 15, quad = lane >> 4;
  int n0 = w * 16;
  floatx4 acc[4];
#pragma unroll
  for (int mt = 0; mt < 4; ++mt) acc[mt] = (floatx4){0.f, 0.f, 0.f, 0.f};
#pragma unroll 1
  for (int cc = 0; cc < 2; ++cc) {
    int c0 = (blockIdx.x * 2 + cc) * PCHUNK;
    // stage coefT slice [64][512] fp32 -> bf16 LDS (coalesced, swizzled)
#pragma unroll 4
    for (int it = 0; it < 16; ++it) {
      int f4 = t + it * 512;                     // 0..8191
      int g = f4 >> 7;
      int k = (f4 & 127) * 4;
      float4 v = *(const float4*)(coefT + (size_t)g * N_PAD + c0 + k);
      ushort4 u;
      u.x = f2bf(v.x); u.y = f2bf(v.y); u.z = f2bf(v.z); u.w = f2bf(v.w);
      uint32_t off = ((uint32_t)g * (PCHUNK * 2) + k * 2) ^ ((g & 7) << 4);
      *(ushort4*)((char*)cs + off) = u;
    }
    __syncthreads();
#pragma unroll 2
    for (int kb = 0; kb < 16; ++kb) {
      int k0c = kb * 32 + quad * 8;
      short8 bfr;
#pragma unroll
      for (int j = 0; j < 8; ++j)
        bfr[j] = (short)h2[(size_t)(c0 + k0c + j) * FEAT + n0 + r];
#pragma unroll
      for (int mt = 0; mt < 4; ++mt) {
        int row = mt * 16 + r;
        uint32_t off = ((uint32_t)row * (PCHUNK * 2) + k0c * 2) ^ ((row & 7) << 4);
        short8 a = *(const short8*)((const char*)cs + off);
        acc[mt] = __builtin_amdgcn_mfma_f32_16x16x32_bf16(a, bfr, acc[mt], 0, 0, 0);
      }
    }
    __syncthreads();
  }
#pragma unroll
  for (int mt = 0; mt < 4; ++mt)
#pragma unroll
    for (int reg = 0; reg < 4; ++reg)
      atomicAdd(&P[(size_t)(mt * 16 + quad * 4 + reg) * FEAT + n0 + r],
                acc[mt][reg]);
}

// ---------------- per-layer FC head --------------------------------------
template <int K, int C, int KSLICE, int RELU_IN, int DIVC, int NSPLIT>
__global__ __launch_bounds__(256) void fc_layer(const float* __restrict__ IN,
                                                const float* __restrict__ W,
                                                const float* __restrict__ Bs,
                                                const float* __restrict__ cntg,
                                                float* __restrict__ OUT) {
  constexpr int CB = (C + 63) / 64;
  int lane = threadIdx.x & 63;
  int gq = threadIdx.x >> 6;
  int bid = blockIdx.x;
  int kp = bid % NSPLIT;
  int rest = bid / NSPLIT;
  int cg = rest % CB;
  int g = (rest / CB) * 4 + gq;
  int c = cg * 64 + lane;
  if (c >= C) return;
  int k0 = kp * KSLICE;
  const float* wp = W + (size_t)k0 * C + c;
  const float* in = IN + (size_t)g * K + k0;
  float cf = 1.f;
  if (DIVC) cf = fmaxf(cntg[g], 1.f);
  float a0 = 0.f, a1 = 0.f, a2 = 0.f, a3 = 0.f;
  float a4 = 0.f, a5 = 0.f, a6 = 0.f, a7 = 0.f;
#pragma unroll 2
  for (int k = 0; k < KSLICE; k += 8) {
    float i0 = in[k + 0], i1 = in[k + 1], i2 = in[k + 2], i3 = in[k + 3];
    float i4 = in[k + 4], i5 = in[k + 5], i6 = in[k + 6], i7 = in[k + 7];
    if (RELU_IN) {
      i0 = fmaxf(i0, 0.f); i1 = fmaxf(i1, 0.f);
      i2 = fmaxf(i2, 0.f); i3 = fmaxf(i3, 0.f);
      i4 = fmaxf(i4, 0.f); i5 = fmaxf(i5, 0.f);
      i6 = fmaxf(i6, 0.f); i7 = fmaxf(i7, 0.f);
    }
    if (DIVC) {
      i0 /= cf; i1 /= cf; i2 /= cf; i3 /= cf;
      i4 /= cf; i5 /= cf; i6 /= cf; i7 /= cf;
    }
    a0 = fmaf(i0, wp[(size_t)(k + 0) * C], a0);
    a1 = fmaf(i1, wp[(size_t)(k + 1) * C], a1);
    a2 = fmaf(i2, wp[(size_t)(k + 2) * C], a2);
    a3 = fmaf(i3, wp[(size_t)(k + 3) * C], a3);
    a4 = fmaf(i4, wp[(size_t)(k + 4) * C], a4);
    a5 = fmaf(i5, wp[(size_t)(k + 5) * C], a5);
    a6 = fmaf(i6, wp[(size_t)(k + 6) * C], a6);
    a7 = fmaf(i7, wp[(size_t)(k + 7) * C], a7);
  }
  float s = ((a0 + a1) + (a2 + a3)) + ((a4 + a5) + (a6 + a7));
  if (NSPLIT == 1) {
    OUT[(size_t)g * C + c] = s + Bs[c];
  } else {
    atomicAdd(&OUT[(size_t)g * C + c], s + (kp == 0 ? Bs[c] : 0.f));
  }
}

// =========================================================================
extern "C" void kernel_launch(void* const* d_in, const int* in_sizes, int n_in,
                              void* d_out, int out_size, void* d_ws, size_t ws_size,
                              hipStream_t stream) {
  const float* x         = (const float*)d_in[0];
  const int*   ei        = (const int*)d_in[1];     // [2][E]: row0 src, row1 dst
  const int*   batch     = (const int*)d_in[2];
  const float* conv_w[3] = {(const float*)d_in[3], (const float*)d_in[5], (const float*)d_in[7]};
  const float* conv_b[3] = {(const float*)d_in[4], (const float*)d_in[6], (const float*)d_in[8]};
  const float* fc_w[5]   = {(const float*)d_in[9],  (const float*)d_in[11],
                            (const float*)d_in[13], (const float*)d_in[15],
                            (const float*)d_in[17]};
  const float* fc_b[5]   = {(const float*)d_in[10], (const float*)d_in[12],
                            (const float*)d_in[14], (const float*)d_in[16],
                            (const float*)d_in[18]};
  const int* e_src = ei;
  const int* e_dst = ei + N_EDGES;
  float* out_f = (float*)d_out;                  // [64][128] fp32  (output 0)
  float* out_y = (float*)d_out + NGRAPH * FEAT;  // [64][10]  fp32  (output 1)

  char* p = (char*)d_ws;
  auto carve = [&](size_t bytes) {
    char* r = p;
    p += (bytes + 255) & ~(size_t)255;
    return r;
  };
  int*    cnt_p   = (int*)carve((size_t)N_NODES * 128);           // 128B-padded counters
  float*  dinv    = (float*)carve(N_NODES * 4);
  int*    csr_ptr = (int*)carve(N_NODES * 4);
  int*    bsums   = (int*)carve(256 * 4);
  int2*   edges   = (int2*)carve((size_t)N_EDGES * 8);            // {src, dinv_s}
  ushort* wbT     = (ushort*)carve((size_t)2 * FEAT * FEAT * 2);  // bf16 W^T conv1/2
  ushort* hbuf    = (ushort*)carve((size_t)N_PAD * FEAT * 2);     // bf16 h1/h2 (padded)
  float*  coefT   = (float*)carve((size_t)NGRAPH * N_PAD * 4);    // fp32 pool coeffs
  // f_sum..Y4 + ticket carved contiguously so one streaming-zero role in
  // prep covers them: 262656 B = 16416 float4.
  float*  f_sum   = (float*)carve(NGRAPH * FEAT * 4);             // P (32768)
  float*  cnt_g   = (float*)carve(NGRAPH * 4);                    // (256)
  int*    ticket  = (int*)carve(256);                             // (256)
  float*  Y2      = (float*)carve(NGRAPH * 512 * 4);              // (131072, atomic)
  float*  Y3      = (float*)carve(NGRAPH * 256 * 4);              // (65536, atomic)
  float*  Y4      = (float*)carve(NGRAPH * 128 * 4);              // (32768, atomic)
  float*  Y1      = (float*)carve(NGRAPH * 1024 * 4);             // fc1 pre-act (no zero)
  // Shared region (16 MB): [rank 3.2M][msl1 12.8M]; msl2 overlays region
  // start. Lifetimes: rank [gemm_rank..fill_csr]; msl1 [gemm_rank..agg1];
  // msl2 [gemm2_strip..agg2] — written after rank & msl1 are both dead.
  char*   region  = carve((size_t)N_EDGES * 4 + (size_t)N_NODES * FEAT * 2);
  int*    rank    = (int*)region;
  ushort* msl1    = (ushort*)(region + (size_t)N_EDGES * 4);
  ushort* msl2    = (ushort*)region;

  const int BLK_N = (N_NODES + 255) / 256;   // 196

  // ---- prep: weight cvt || coefT zero || cnt_p zero || f_sum..ticket..Y4 zero
  prep_fused<<<PREP_BLKS, 256, 0, stream>>>(conv_w[0], conv_w[1], wbT, coefT,
                                            (float4*)cnt_p, (float4*)f_sum);

  // ---- K1: conv1 gemm || rank atomics ----
  gemm_rank<<<GR_BLKS, 256, 0, stream>>>(x, wbT, msl1, e_dst, cnt_p, rank);

  // ---- dinv + coefT self-term + graph counts + scan1 + scan2 (fused) ----
  dinv_scan1<<<BLK_N, 256, 0, stream>>>(cnt_p, batch, dinv, cnt_g, csr_ptr,
                                        bsums, coefT, ticket);

  // ---- CSR fill (atomic-free; bsums folded in) ----
  fill_csr<<<E_BLKS, 256, 0, stream>>>(e_src, e_dst, rank, csr_ptr, bsums,
                                       dinv, edges);

  // ---- conv1 agg + row-local coefT edge atomics ----
  agg_pass<1><<<AGG_BLKS, 256, 0, stream>>>(msl1, dinv, csr_ptr, bsums, cnt_p,
                                            edges, conv_b[0], hbuf, batch, coefT);
  // ---- conv2 gemm (row-strip): msl2 = h1 @ W2 ----
  gemm2_strip<<<GSTRIP_BLKS, 256, 0, stream>>>(hbuf, wbT + FEAT * FEAT, msl2);
  // ---- conv2 agg (pure) ----
  agg_pass<0><<<AGG_BLKS, 256, 0, stream>>>(msl2, dinv, csr_ptr, bsums, cnt_p,
                                            edges, conv_b[1], hbuf, batch, coefT);
  // ---- conv3 + pool fused algebraically: P = coefT @ h2 (MFMA) ----
  pool_mfma<<<NCHUNKS / 2, 512, 0, stream>>>(hbuf, coefT, f_sum);

  // ---- per-layer head: Pn@W3 -> fc1..fc5 (stream-ordered) ----
  fc_layer< 128, 128, 128, 0, 1, 1><<< 32, 256, 0, stream>>>(f_sum, conv_w[2], conv_b[2], cnt_g, out_f);
  fc_layer< 128,1024, 128, 0, 0, 1><<<256, 256, 0, stream>>>(out_f, fc_w[0], fc_b[0], nullptr, Y1);
  fc_layer<1024, 512, 256, 1, 0, 4><<<512, 256, 0, stream>>>(Y1, fc_w[1], fc_b[1], nullptr, Y2);
  fc_layer< 512, 256, 128, 1, 0, 4><<<256, 256, 0, stream>>>(Y2, fc_w[2], fc_b[2], nullptr, Y3);
  fc_layer< 256, 128,  32, 1, 0, 8><<<256, 256, 0, stream>>>(Y3, fc_w[3], fc_b[3], nullptr, Y4);
  fc_layer< 128,  10, 128, 1, 0, 1><<< 16, 256, 0, stream>>>(Y4, fc_w[4], fc_b[4], nullptr, out_y);
}

// Round 15
// 330.415 us; speedup vs baseline: 1.0314x; 1.0314x over previous
//
#include <hip/hip_runtime.h>
#include <stdint.h>

#define N_NODES 50000
#define N_EDGES 800000
#define N_PAD   50176    // 98 * 512, K-padding for MFMA pool
#define PCHUNK  512
#define NCHUNKS 98
#define FEAT    128
#define NGRAPH  64

#define E_BLKS      3125   // 800000 edges / 256
#define GSTRIP_BLKS 782    // ceil(3125 row-strips / 4 waves)
#define GR_BLKS     (GSTRIP_BLKS + E_BLKS)   // interleaved 1:4
#define CZ_BLKS     3136   // 64*N_PAD*4B / (256 thr * 16B)
#define CP_BLKS     1563   // cnt_p zero: 400000 float4 / 256
#define Z2_BLKS     65     // f_sum..Y4 zero: 16400 float4 / 256
#define PREP_BLKS   (32 + CZ_BLKS + CP_BLKS + Z2_BLKS)
#define E1_SPLIT    399872 // coef edges: agg1 takes [0,E1), agg2 [E1,E)
#define AGGC_GRID   (1563 * 9)   // 12504 agg-role + 1563 coef-role blocks

typedef __attribute__((ext_vector_type(8))) short short8;
typedef __attribute__((ext_vector_type(4))) float floatx4;

static __device__ __forceinline__ ushort f2bf(float f) {
  uint32_t x = __float_as_uint(f);
  x += 0x7FFF + ((x >> 16) & 1);   // RNE
  return (ushort)(x >> 16);
}
static __device__ __forceinline__ float bfLo(uint32_t u) {
  return __uint_as_float(u << 16);
}
static __device__ __forceinline__ float bfHi(uint32_t u) {
  return __uint_as_float(u & 0xFFFF0000u);
}

// cvt + transpose: in is row-major [128][128] fp32 [k][n], out is [n][k] bf16
static __device__ __forceinline__ void cvt4T(const float* __restrict__ in,
                                             ushort* __restrict__ outT, int i) {
  float4 v = ((const float4*)in)[i];
  int k = (4 * i) >> 7;          // row
  int n = (4 * i) & 127;         // col
  outT[(size_t)(n + 0) * FEAT + k] = f2bf(v.x);
  outT[(size_t)(n + 1) * FEAT + k] = f2bf(v.y);
  outT[(size_t)(n + 2) * FEAT + k] = f2bf(v.z);
  outT[(size_t)(n + 3) * FEAT + k] = f2bf(v.w);
}

// ---- prep: weight transpose-cvt + all workspace zeroing (memsets folded)
__global__ __launch_bounds__(256) void prep_fused(const float* __restrict__ w0,
                                                  const float* __restrict__ w1,
                                                  ushort* __restrict__ wbT,
                                                  float* __restrict__ coefT,
                                                  float4* __restrict__ zcnt,
                                                  float4* __restrict__ zfy) {
  int b = blockIdx.x, t = threadIdx.x;
  if (b < 32) {
    int i = b * 256 + t;                       // 0..8191
    if (i < 4096) cvt4T(w0, wbT, i);
    else cvt4T(w1, wbT + FEAT * FEAT, i - 4096);
  } else if (b < 32 + CZ_BLKS) {
    int i = (b - 32) * 256 + t;                // 0..802815 exactly
    ((float4*)coefT)[i] = make_float4(0.f, 0.f, 0.f, 0.f);
  } else if (b < 32 + CZ_BLKS + CP_BLKS) {
    int i = (b - 32 - CZ_BLKS) * 256 + t;      // cnt_p: 400000 float4
    if (i < 400000) zcnt[i] = make_float4(0.f, 0.f, 0.f, 0.f);
  } else {
    int i = (b - 32 - CZ_BLKS - CP_BLKS) * 256 + t;   // f_sum..Y4: 16400 float4
    if (i < 16400) zfy[i] = make_float4(0.f, 0.f, 0.f, 0.f);
  }
}

// ---- row-strip gemm, A from fp32 (in-reg cvt): wave owns 16x128 strip ---
static __device__ __forceinline__ void gemm_strip_f32a(int strip, int lane,
                                                       const float* __restrict__ X,
                                                       const ushort* __restrict__ WT,
                                                       ushort* __restrict__ XW) {
  if (strip >= N_NODES / 16) return;
  int m0 = strip * 16;
  int r = lane & 15, quad = lane >> 4;
  const float* xrow = X + (size_t)(m0 + r) * FEAT;
  short8 afr[4];
#pragma unroll
  for (int kb = 0; kb < 4; ++kb) {
    int k0 = kb * 32 + quad * 8;
    float4 f0 = *(const float4*)(xrow + k0);
    float4 f1 = *(const float4*)(xrow + k0 + 4);
    short8 a;
    a[0] = (short)f2bf(f0.x); a[1] = (short)f2bf(f0.y);
    a[2] = (short)f2bf(f0.z); a[3] = (short)f2bf(f0.w);
    a[4] = (short)f2bf(f1.x); a[5] = (short)f2bf(f1.y);
    a[6] = (short)f2bf(f1.z); a[7] = (short)f2bf(f1.w);
    afr[kb] = a;
  }
#pragma unroll
  for (int nt = 0; nt < 8; ++nt) {
    int n0 = nt * 16;
    floatx4 acc = {0.f, 0.f, 0.f, 0.f};
    const ushort* wrow = WT + (size_t)(n0 + r) * FEAT;
#pragma unroll
    for (int kb = 0; kb < 4; ++kb) {
      short8 b = *(const short8*)(wrow + kb * 32 + quad * 8);
      acc = __builtin_amdgcn_mfma_f32_16x16x32_bf16(afr[kb], b, acc, 0, 0, 0);
    }
#pragma unroll
    for (int reg = 0; reg < 4; ++reg)
      XW[(size_t)(m0 + quad * 4 + reg) * FEAT + n0 + r] = f2bf(acc[reg]);
  }
}

// ---- K1: conv1 gemm (row-strip) interleaved 1:4 with rank atomics -------
// cnt_p is 128B-padded (cnt_p[dst*32]): each counter owns a full line.
__global__ __launch_bounds__(256) void gemm_rank(const float* __restrict__ x,
                                                 const ushort* __restrict__ wbT,
                                                 ushort* __restrict__ msl,
                                                 const int* __restrict__ dst,
                                                 int* __restrict__ cnt_p,
                                                 int* __restrict__ rank) {
  int b = blockIdx.x, t = threadIdx.x;
  int fifth = b / 5;
  if (b - fifth * 5 == 0) {
    gemm_strip_f32a(fifth * 4 + (t >> 6), t & 63, x, wbT, msl);
  } else {
    int e = (b - fifth - 1) * 256 + t;         // 0..799999 exactly
    rank[e] = atomicAdd(&cnt_p[dst[e] * 32], 1);
  }
}

// ---- conv2 gemm: row-strip, A bf16 (loaded once, 8 n-tiles reuse) -------
__global__ __launch_bounds__(256) void gemm2_strip(const ushort* __restrict__ X,
                                                   const ushort* __restrict__ WT,
                                                   ushort* __restrict__ XW) {
  int strip = (blockIdx.x * 256 + threadIdx.x) >> 6;
  int lane = threadIdx.x & 63;
  if (strip >= N_NODES / 16) return;
  int m0 = strip * 16;
  int r = lane & 15, quad = lane >> 4;
  const ushort* xrow = X + (size_t)(m0 + r) * FEAT;
  short8 afr[4];
#pragma unroll
  for (int kb = 0; kb < 4; ++kb)
    afr[kb] = *(const short8*)(xrow + kb * 32 + quad * 8);
#pragma unroll
  for (int nt = 0; nt < 8; ++nt) {
    int n0 = nt * 16;
    floatx4 acc = {0.f, 0.f, 0.f, 0.f};
    const ushort* wrow = WT + (size_t)(n0 + r) * FEAT;
#pragma unroll
    for (int kb = 0; kb < 4; ++kb) {
      short8 b = *(const short8*)(wrow + kb * 32 + quad * 8);
      acc = __builtin_amdgcn_mfma_f32_16x16x32_bf16(afr[kb], b, acc, 0, 0, 0);
    }
#pragma unroll
    for (int reg = 0; reg < 4; ++reg)
      XW[(size_t)(m0 + quad * 4 + reg) * FEAT + n0 + r] = f2bf(acc[reg]);
  }
}

// ---- fused: dinv + coefT self-term + graph counts + scan1 ---------------
// ptr stays block-local exclusive; consumers add bsums[v>>8] (scan3 folded).
__global__ __launch_bounds__(256) void dinv_scan1(const int* __restrict__ cnt_p,
                                                  const int* __restrict__ batch,
                                                  float* __restrict__ dinv,
                                                  float* __restrict__ cnt_g,
                                                  int* __restrict__ ptr,
                                                  int* __restrict__ bsums,
                                                  float* __restrict__ coefT) {
  __shared__ int tmp[256];
  __shared__ int bins[NGRAPH];
  if (threadIdx.x < NGRAPH) bins[threadIdx.x] = 0;
  int i = blockIdx.x * 256 + threadIdx.x;
  int v = (i < N_NODES) ? cnt_p[i * 32] : 0;
  tmp[threadIdx.x] = v;
  __syncthreads();
  for (int off = 1; off < 256; off <<= 1) {
    int t = (threadIdx.x >= off) ? tmp[threadIdx.x - off] : 0;
    __syncthreads();
    tmp[threadIdx.x] += t;
    __syncthreads();
  }
  if (i < N_NODES) ptr[i] = tmp[threadIdx.x] - v;           // block-local excl
  if (threadIdx.x == 255) bsums[blockIdx.x] = tmp[255];
  if (i < N_NODES) {
    float di = rsqrtf((float)v + 1.0f);
    dinv[i] = di;
    int g = batch[i];
    coefT[(size_t)g * N_PAD + i] = di * di;   // self term (coalesced: sorted)
    atomicAdd(&bins[g], 1);
  }
  __syncthreads();
  if (threadIdx.x < NGRAPH && bins[threadIdx.x] > 0)
    atomicAdd(&cnt_g[threadIdx.x], (float)bins[threadIdx.x]);
}

__global__ __launch_bounds__(256) void scan2(int* __restrict__ bsums, int nb) {
  __shared__ int tmp[256];
  int v = (threadIdx.x < nb) ? bsums[threadIdx.x] : 0;
  tmp[threadIdx.x] = v;
  __syncthreads();
  for (int off = 1; off < 256; off <<= 1) {
    int t = (threadIdx.x >= off) ? tmp[threadIdx.x - off] : 0;
    __syncthreads();
    tmp[threadIdx.x] += t;
    __syncthreads();
  }
  if (threadIdx.x < nb) bsums[threadIdx.x] = tmp[threadIdx.x] - v;  // exclusive
}

// ---- fill: atomic-free CSR scatter, payload {src, dinv[src]} ------------
__global__ __launch_bounds__(256) void fill_csr(const int* __restrict__ src,
                                                const int* __restrict__ dst,
                                                const int* __restrict__ rank,
                                                const int* __restrict__ ptr,
                                                const int* __restrict__ bsums,
                                                const float* __restrict__ dinv,
                                                int2* __restrict__ edges) {
  int e = blockIdx.x * 256 + threadIdx.x;
  if (e >= N_EDGES) return;
  int s = src[e];
  int d = dst[e];
  edges[ptr[d] + bsums[d >> 8] + rank[e]] = make_int2(s, __float_as_int(dinv[s]));
}

// ---- edge-gather accumulator (16/8/4/2/1-edge ILP) ----------------------
static __device__ __forceinline__ float2 agg_node(const uint32_t* __restrict__ m32,
                                                  const int2* __restrict__ edges,
                                                  int start, int n, int lane) {
  float ax0 = 0.f, ay0 = 0.f, ax1 = 0.f, ay1 = 0.f;
  float ax2 = 0.f, ay2 = 0.f, ax3 = 0.f, ay3 = 0.f;
  int i = 0;
  if ((start & 1) && n > 0) {                   // align to int4 (2-edge) bound
    int2 e = edges[start];
    uint32_t u = m32[(size_t)e.x * 64 + lane];
    float nrm = __int_as_float(e.y);
    ax0 = fmaf(nrm, bfLo(u), ax0);
    ay0 = fmaf(nrm, bfHi(u), ay0);
    i = 1;
  }
  for (; i + 16 <= n; i += 16) {
    const int4* ep = (const int4*)(edges + start + i);   // 16B-aligned
    int4 q0 = ep[0], q1 = ep[1], q2 = ep[2], q3 = ep[3];
    int4 q4 = ep[4], q5 = ep[5], q6 = ep[6], q7 = ep[7];
    uint32_t u0 = m32[(size_t)q0.x * 64 + lane];
    uint32_t u1 = m32[(size_t)q0.z * 64 + lane];
    uint32_t u2 = m32[(size_t)q1.x * 64 + lane];
    uint32_t u3 = m32[(size_t)q1.z * 64 + lane];
    uint32_t u4 = m32[(size_t)q2.x * 64 + lane];
    uint32_t u5 = m32[(size_t)q2.z * 64 + lane];
    uint32_t u6 = m32[(size_t)q3.x * 64 + lane];
    uint32_t u7 = m32[(size_t)q3.z * 64 + lane];
    uint32_t u8 = m32[(size_t)q4.x * 64 + lane];
    uint32_t u9 = m32[(size_t)q4.z * 64 + lane];
    uint32_t uA = m32[(size_t)q5.x * 64 + lane];
    uint32_t uB = m32[(size_t)q5.z * 64 + lane];
    uint32_t uC = m32[(size_t)q6.x * 64 + lane];
    uint32_t uD = m32[(size_t)q6.z * 64 + lane];
    uint32_t uE = m32[(size_t)q7.x * 64 + lane];
    uint32_t uF = m32[(size_t)q7.z * 64 + lane];
    float n0 = __int_as_float(q0.y), n1 = __int_as_float(q0.w);
    float n2 = __int_as_float(q1.y), n3 = __int_as_float(q1.w);
    float n4 = __int_as_float(q2.y), n5 = __int_as_float(q2.w);
    float n6 = __int_as_float(q3.y), n7 = __int_as_float(q3.w);
    float n8 = __int_as_float(q4.y), n9 = __int_as_float(q4.w);
    float nA = __int_as_float(q5.y), nB = __int_as_float(q5.w);
    float nC = __int_as_float(q6.y), nD = __int_as_float(q6.w);
    float nE = __int_as_float(q7.y), nF = __int_as_float(q7.w);
    ax0 = fmaf(n0, bfLo(u0), ax0); ay0 = fmaf(n0, bfHi(u0), ay0);
    ax1 = fmaf(n1, bfLo(u1), ax1); ay1 = fmaf(n1, bfHi(u1), ay1);
    ax2 = fmaf(n2, bfLo(u2), ax2); ay2 = fmaf(n2, bfHi(u2), ay2);
    ax3 = fmaf(n3, bfLo(u3), ax3); ay3 = fmaf(n3, bfHi(u3), ay3);
    ax0 = fmaf(n4, bfLo(u4), ax0); ay0 = fmaf(n4, bfHi(u4), ay0);
    ax1 = fmaf(n5, bfLo(u5), ax1); ay1 = fmaf(n5, bfHi(u5), ay1);
    ax2 = fmaf(n6, bfLo(u6), ax2); ay2 = fmaf(n6, bfHi(u6), ay2);
    ax3 = fmaf(n7, bfLo(u7), ax3); ay3 = fmaf(n7, bfHi(u7), ay3);
    ax0 = fmaf(n8, bfLo(u8), ax0); ay0 = fmaf(n8, bfHi(u8), ay0);
    ax1 = fmaf(n9, bfLo(u9), ax1); ay1 = fmaf(n9, bfHi(u9), ay1);
    ax2 = fmaf(nA, bfLo(uA), ax2); ay2 = fmaf(nA, bfHi(uA), ay2);
    ax3 = fmaf(nB, bfLo(uB), ax3); ay3 = fmaf(nB, bfHi(uB), ay3);
    ax0 = fmaf(nC, bfLo(uC), ax0); ay0 = fmaf(nC, bfHi(uC), ay0);
    ax1 = fmaf(nD, bfLo(uD), ax1); ay1 = fmaf(nD, bfHi(uD), ay1);
    ax2 = fmaf(nE, bfLo(uE), ax2); ay2 = fmaf(nE, bfHi(uE), ay2);
    ax3 = fmaf(nF, bfLo(uF), ax3); ay3 = fmaf(nF, bfHi(uF), ay3);
  }
  if (i + 8 <= n) {
    const int4* ep = (const int4*)(edges + start + i);
    int4 q0 = ep[0], q1 = ep[1], q2 = ep[2], q3 = ep[3];
    uint32_t u0 = m32[(size_t)q0.x * 64 + lane];
    uint32_t u1 = m32[(size_t)q0.z * 64 + lane];
    uint32_t u2 = m32[(size_t)q1.x * 64 + lane];
    uint32_t u3 = m32[(size_t)q1.z * 64 + lane];
    uint32_t u4 = m32[(size_t)q2.x * 64 + lane];
    uint32_t u5 = m32[(size_t)q2.z * 64 + lane];
    uint32_t u6 = m32[(size_t)q3.x * 64 + lane];
    uint32_t u7 = m32[(size_t)q3.z * 64 + lane];
    float n0 = __int_as_float(q0.y), n1 = __int_as_float(q0.w);
    float n2 = __int_as_float(q1.y), n3 = __int_as_float(q1.w);
    float n4 = __int_as_float(q2.y), n5 = __int_as_float(q2.w);
    float n6 = __int_as_float(q3.y), n7 = __int_as_float(q3.w);
    ax0 = fmaf(n0, bfLo(u0), ax0); ay0 = fmaf(n0, bfHi(u0), ay0);
    ax1 = fmaf(n1, bfLo(u1), ax1); ay1 = fmaf(n1, bfHi(u1), ay1);
    ax2 = fmaf(n2, bfLo(u2), ax2); ay2 = fmaf(n2, bfHi(u2), ay2);
    ax3 = fmaf(n3, bfLo(u3), ax3); ay3 = fmaf(n3, bfHi(u3), ay3);
    ax0 = fmaf(n4, bfLo(u4), ax0); ay0 = fmaf(n4, bfHi(u4), ay0);
    ax1 = fmaf(n5, bfLo(u5), ax1); ay1 = fmaf(n5, bfHi(u5), ay1);
    ax2 = fmaf(n6, bfLo(u6), ax2); ay2 = fmaf(n6, bfHi(u6), ay2);
    ax3 = fmaf(n7, bfLo(u7), ax3); ay3 = fmaf(n7, bfHi(u7), ay3);
    i += 8;
  }
  if (i + 4 <= n) {                             // 4-edge mid tail
    const int4* ep = (const int4*)(edges + start + i);
    int4 q0 = ep[0], q1 = ep[1];
    uint32_t u0 = m32[(size_t)q0.x * 64 + lane];
    uint32_t u1 = m32[(size_t)q0.z * 64 + lane];
    uint32_t u2 = m32[(size_t)q1.x * 64 + lane];
    uint32_t u3 = m32[(size_t)q1.z * 64 + lane];
    float n0 = __int_as_float(q0.y), n1 = __int_as_float(q0.w);
    float n2 = __int_as_float(q1.y), n3 = __int_as_float(q1.w);
    ax0 = fmaf(n0, bfLo(u0), ax0); ay0 = fmaf(n0, bfHi(u0), ay0);
    ax1 = fmaf(n1, bfLo(u1), ax1); ay1 = fmaf(n1, bfHi(u1), ay1);
    ax2 = fmaf(n2, bfLo(u2), ax2); ay2 = fmaf(n2, bfHi(u2), ay2);
    ax3 = fmaf(n3, bfLo(u3), ax3); ay3 = fmaf(n3, bfHi(u3), ay3);
    i += 4;
  }
  if (i + 2 <= n) {                             // 2-edge tail
    const int4* ep = (const int4*)(edges + start + i);
    int4 q0 = ep[0];
    uint32_t u0 = m32[(size_t)q0.x * 64 + lane];
    uint32_t u1 = m32[(size_t)q0.z * 64 + lane];
    float n0 = __int_as_float(q0.y), n1 = __int_as_float(q0.w);
    ax0 = fmaf(n0, bfLo(u0), ax0); ay0 = fmaf(n0, bfHi(u0), ay0);
    ax1 = fmaf(n1, bfLo(u1), ax1); ay1 = fmaf(n1, bfHi(u1), ay1);
    i += 2;
  }
  for (; i < n; ++i) {
    int2 e = edges[start + i];
    float nrm = __int_as_float(e.y);
    uint32_t u = m32[(size_t)e.x * 64 + lane];
    ax0 = fmaf(nrm, bfLo(u), ax0);
    ay0 = fmaf(nrm, bfHi(u), ay0);
  }
  return make_float2((ax0 + ax1) + (ax2 + ax3), (ay0 + ay1) + (ay2 + ay3));
}

// ---- one node's full agg epilogue (bf16 relu out) -----------------------
static __device__ __forceinline__ void agg_one(int v, int lane,
                                               const ushort* __restrict__ msg,
                                               const float* __restrict__ dinv,
                                               const int* __restrict__ ptr,
                                               const int* __restrict__ bsums,
                                               const int* __restrict__ cnt_p,
                                               const int2* __restrict__ edges,
                                               const float* __restrict__ bias,
                                               ushort* __restrict__ outp) {
  float di = dinv[v];
  const uint32_t* m32 = (const uint32_t*)msg;
  uint32_t su = m32[(size_t)v * 64 + lane];
  int start = ptr[v] + bsums[v >> 8];
  float2 s = agg_node(m32, edges, start, cnt_p[v * 32], lane);
  float ax = fmaf(fmaf(di, bfLo(su), s.x), di, bias[2 * lane]);
  float ay = fmaf(fmaf(di, bfHi(su), s.y), di, bias[2 * lane + 1]);
  ushort2 h2;
  h2.x = f2bf(fmaxf(ax, 0.f));
  h2.y = f2bf(fmaxf(ay, 0.f));
  ((ushort2*)outp)[(size_t)v * 64 + lane] = h2;
}

// ---- agg pass interleaved 8:1 with HALF the coefT edge atomics ----------
// PHASE 0 handles coef edges [0, E1_SPLIT), PHASE 1 [E1_SPLIT, N_EDGES).
template <int PHASE>
__global__ __launch_bounds__(256) void agg_coef(const ushort* __restrict__ msg,
                                                const float* __restrict__ dinv,
                                                const int* __restrict__ ptr,
                                                const int* __restrict__ bsums,
                                                const int* __restrict__ cnt_p,
                                                const int2* __restrict__ edges,
                                                const float* __restrict__ bias,
                                                ushort* __restrict__ outp,
                                                const int* __restrict__ src,
                                                const int* __restrict__ dst,
                                                const int* __restrict__ batch,
                                                float* __restrict__ coefT) {
  int b = blockIdx.x, t = threadIdx.x;
  int grp = b / 9;
  int rem = b - grp * 9;
  if (rem < 8) {
    int ab = grp * 8 + rem;                    // 0..12503
    if (ab >= 12500) return;
    agg_one(ab * 4 + (t >> 6), t & 63, msg, dinv, ptr, bsums, cnt_p, edges,
            bias, outp);
  } else {
    int e = (PHASE ? E1_SPLIT : 0) + grp * 256 + t;
    if (e < (PHASE ? N_EDGES : E1_SPLIT)) {
      int s = src[e], d = dst[e];
      atomicAdd(&coefT[(size_t)batch[d] * N_PAD + s], dinv[s] * dinv[d]);
    }
  }
}

// ---- pool v2: P = coefT x h2 via MFMA, coefT staged to LDS (bf16) -------
__global__ __launch_bounds__(512) void pool_mfma(const ushort* __restrict__ h2,
                                                 const float* __restrict__ coefT,
                                                 float* __restrict__ P) {
  __shared__ ushort cs[64 * PCHUNK];             // 64 KB
  int t = threadIdx.x;
  int lane = t & 63;
  int w = t >> 6;                                // wave = n-tile 0..7
  int r = lane & 15, quad = lane >> 4;
  int n0 = w * 16;
  floatx4 acc[4];
#pragma unroll
  for (int mt = 0; mt < 4; ++mt) acc[mt] = (floatx4){0.f, 0.f, 0.f, 0.f};
#pragma unroll 1
  for (int cc = 0; cc < 2; ++cc) {
    int c0 = (blockIdx.x * 2 + cc) * PCHUNK;
    // stage coefT slice [64][512] fp32 -> bf16 LDS (coalesced, swizzled)
#pragma unroll 4
    for (int it = 0; it < 16; ++it) {
      int f4 = t + it * 512;                     // 0..8191
      int g = f4 >> 7;
      int k = (f4 & 127) * 4;
      float4 v = *(const float4*)(coefT + (size_t)g * N_PAD + c0 + k);
      ushort4 u;
      u.x = f2bf(v.x); u.y = f2bf(v.y); u.z = f2bf(v.z); u.w = f2bf(v.w);
      uint32_t off = ((uint32_t)g * (PCHUNK * 2) + k * 2) ^ ((g & 7) << 4);
      *(ushort4*)((char*)cs + off) = u;
    }
    __syncthreads();
#pragma unroll 2
    for (int kb = 0; kb < 16; ++kb) {
      int k0c = kb * 32 + quad * 8;
      short8 bfr;
#pragma unroll
      for (int j = 0; j < 8; ++j)
        bfr[j] = (short)h2[(size_t)(c0 + k0c + j) * FEAT + n0 + r];
#pragma unroll
      for (int mt = 0; mt < 4; ++mt) {
        int row = mt * 16 + r;
        uint32_t off = ((uint32_t)row * (PCHUNK * 2) + k0c * 2) ^ ((row & 7) << 4);
        short8 a = *(const short8*)((const char*)cs + off);
        acc[mt] = __builtin_amdgcn_mfma_f32_16x16x32_bf16(a, bfr, acc[mt], 0, 0, 0);
      }
    }
    __syncthreads();
  }
#pragma unroll
  for (int mt = 0; mt < 4; ++mt)
#pragma unroll
    for (int reg = 0; reg < 4; ++reg)
      atomicAdd(&P[(size_t)(mt * 16 + quad * 4 + reg) * FEAT + n0 + r],
                acc[mt][reg]);
}

// ---------------- per-layer FC head --------------------------------------
template <int K, int C, int KSLICE, int RELU_IN, int DIVC, int NSPLIT>
__global__ __launch_bounds__(256) void fc_layer(const float* __restrict__ IN,
                                                const float* __restrict__ W,
                                                const float* __restrict__ Bs,
                                                const float* __restrict__ cntg,
                                                float* __restrict__ OUT) {
  constexpr int CB = (C + 63) / 64;
  int lane = threadIdx.x & 63;
  int gq = threadIdx.x >> 6;
  int bid = blockIdx.x;
  int kp = bid % NSPLIT;
  int rest = bid / NSPLIT;
  int cg = rest % CB;
  int g = (rest / CB) * 4 + gq;
  int c = cg * 64 + lane;
  if (c >= C) return;
  int k0 = kp * KSLICE;
  const float* wp = W + (size_t)k0 * C + c;
  const float* in = IN + (size_t)g * K + k0;
  float cf = 1.f;
  if (DIVC) cf = fmaxf(cntg[g], 1.f);
  float a0 = 0.f, a1 = 0.f, a2 = 0.f, a3 = 0.f;
  float a4 = 0.f, a5 = 0.f, a6 = 0.f, a7 = 0.f;
#pragma unroll 2
  for (int k = 0; k < KSLICE; k += 8) {
    float i0 = in[k + 0], i1 = in[k + 1], i2 = in[k + 2], i3 = in[k + 3];
    float i4 = in[k + 4], i5 = in[k + 5], i6 = in[k + 6], i7 = in[k + 7];
    if (RELU_IN) {
      i0 = fmaxf(i0, 0.f); i1 = fmaxf(i1, 0.f);
      i2 = fmaxf(i2, 0.f); i3 = fmaxf(i3, 0.f);
      i4 = fmaxf(i4, 0.f); i5 = fmaxf(i5, 0.f);
      i6 = fmaxf(i6, 0.f); i7 = fmaxf(i7, 0.f);
    }
    if (DIVC) {
      i0 /= cf; i1 /= cf; i2 /= cf; i3 /= cf;
      i4 /= cf; i5 /= cf; i6 /= cf; i7 /= cf;
    }
    a0 = fmaf(i0, wp[(size_t)(k + 0) * C], a0);
    a1 = fmaf(i1, wp[(size_t)(k + 1) * C], a1);
    a2 = fmaf(i2, wp[(size_t)(k + 2) * C], a2);
    a3 = fmaf(i3, wp[(size_t)(k + 3) * C], a3);
    a4 = fmaf(i4, wp[(size_t)(k + 4) * C], a4);
    a5 = fmaf(i5, wp[(size_t)(k + 5) * C], a5);
    a6 = fmaf(i6, wp[(size_t)(k + 6) * C], a6);
    a7 = fmaf(i7, wp[(size_t)(k + 7) * C], a7);
  }
  float s = ((a0 + a1) + (a2 + a3)) + ((a4 + a5) + (a6 + a7));
  if (NSPLIT == 1) {
    OUT[(size_t)g * C + c] = s + Bs[c];
  } else {
    atomicAdd(&OUT[(size_t)g * C + c], s + (kp == 0 ? Bs[c] : 0.f));
  }
}

// =========================================================================
extern "C" void kernel_launch(void* const* d_in, const int* in_sizes, int n_in,
                              void* d_out, int out_size, void* d_ws, size_t ws_size,
                              hipStream_t stream) {
  const float* x         = (const float*)d_in[0];
  const int*   ei        = (const int*)d_in[1];     // [2][E]: row0 src, row1 dst
  const int*   batch     = (const int*)d_in[2];
  const float* conv_w[3] = {(const float*)d_in[3], (const float*)d_in[5], (const float*)d_in[7]};
  const float* conv_b[3] = {(const float*)d_in[4], (const float*)d_in[6], (const float*)d_in[8]};
  const float* fc_w[5]   = {(const float*)d_in[9],  (const float*)d_in[11],
                            (const float*)d_in[13], (const float*)d_in[15],
                            (const float*)d_in[17]};
  const float* fc_b[5]   = {(const float*)d_in[10], (const float*)d_in[12],
                            (const float*)d_in[14], (const float*)d_in[16],
                            (const float*)d_in[18]};
  const int* e_src = ei;
  const int* e_dst = ei + N_EDGES;
  float* out_f = (float*)d_out;                  // [64][128] fp32  (output 0)
  float* out_y = (float*)d_out + NGRAPH * FEAT;  // [64][10]  fp32  (output 1)

  char* p = (char*)d_ws;
  auto carve = [&](size_t bytes) {
    char* r = p;
    p += (bytes + 255) & ~(size_t)255;
    return r;
  };
  int*    cnt_p   = (int*)carve((size_t)N_NODES * 128);           // 128B-padded counters
  float*  dinv    = (float*)carve(N_NODES * 4);
  int*    csr_ptr = (int*)carve(N_NODES * 4);
  int*    bsums   = (int*)carve(256 * 4);
  int2*   edges   = (int2*)carve((size_t)N_EDGES * 8);            // {src, dinv_s}
  ushort* wbT     = (ushort*)carve((size_t)2 * FEAT * FEAT * 2);  // bf16 W^T conv1/2
  ushort* hbuf    = (ushort*)carve((size_t)N_PAD * FEAT * 2);     // bf16 h1/h2 (padded)
  float*  coefT   = (float*)carve((size_t)NGRAPH * N_PAD * 4);    // fp32 pool coeffs
  // f_sum..Y4 carved contiguously (all 256-multiples, no gaps) so one
  // streaming-zero role in prep_fused covers them: 262400 B = 16400 float4.
  float*  f_sum   = (float*)carve(NGRAPH * FEAT * 4);             // P (32768)
  float*  cnt_g   = (float*)carve(NGRAPH * 4);                    // (256)
  float*  Y2      = (float*)carve(NGRAPH * 512 * 4);              // (131072, atomic)
  float*  Y3      = (float*)carve(NGRAPH * 256 * 4);              // (65536, atomic)
  float*  Y4      = (float*)carve(NGRAPH * 128 * 4);              // (32768, atomic)
  float*  Y1      = (float*)carve(NGRAPH * 1024 * 4);             // fc1 pre-act (no zero)
  // Shared region (16 MB): [rank 3.2M][msl1 12.8M]; msl2 overlays region
  // start. Lifetimes: rank [gemm_rank..fill_csr]; msl1 [gemm_rank..agg1];
  // msl2 [gemm2_strip..agg2] — written after rank & msl1 are both dead.
  char*   region  = carve((size_t)N_EDGES * 4 + (size_t)N_NODES * FEAT * 2);
  int*    rank    = (int*)region;
  ushort* msl1    = (ushort*)(region + (size_t)N_EDGES * 4);
  ushort* msl2    = (ushort*)region;

  const int BLK_N = (N_NODES + 255) / 256;   // 196

  // ---- prep: weight cvt || coefT zero || cnt_p zero || f_sum..Y4 zero ----
  prep_fused<<<PREP_BLKS, 256, 0, stream>>>(conv_w[0], conv_w[1], wbT, coefT,
                                            (float4*)cnt_p, (float4*)f_sum);

  // ---- K1: conv1 gemm || rank atomics ----
  gemm_rank<<<GR_BLKS, 256, 0, stream>>>(x, wbT, msl1, e_dst, cnt_p, rank);

  // ---- dinv + coefT self-term + graph counts + scan1 ----
  dinv_scan1<<<BLK_N, 256, 0, stream>>>(cnt_p, batch, dinv, cnt_g, csr_ptr,
                                        bsums, coefT);
  scan2<<<1, 256, 0, stream>>>(bsums, BLK_N);

  // ---- CSR fill (atomic-free; bsums folded in) ----
  fill_csr<<<E_BLKS, 256, 0, stream>>>(e_src, e_dst, rank, csr_ptr, bsums,
                                       dinv, edges);

  // ---- conv1 agg || coef edges half A (8:1 interleave) ----
  agg_coef<0><<<AGGC_GRID, 256, 0, stream>>>(
      msl1, dinv, csr_ptr, bsums, cnt_p, edges, conv_b[0], hbuf,
      e_src, e_dst, batch, coefT);
  // ---- conv2 gemm (row-strip): msl2 = h1 @ W2 ----
  gemm2_strip<<<GSTRIP_BLKS, 256, 0, stream>>>(hbuf, wbT + FEAT * FEAT, msl2);
  // ---- conv2 agg || coef edges half B ----
  agg_coef<1><<<AGGC_GRID, 256, 0, stream>>>(
      msl2, dinv, csr_ptr, bsums, cnt_p, edges, conv_b[1], hbuf,
      e_src, e_dst, batch, coefT);
  // ---- conv3 + pool fused algebraically: P = coefT @ h2 (MFMA) ----
  pool_mfma<<<NCHUNKS / 2, 512, 0, stream>>>(hbuf, coefT, f_sum);

  // ---- per-layer head: Pn@W3 -> fc1..fc5 (stream-ordered) ----
  fc_layer< 128, 128, 128, 0, 1, 1><<< 32, 256, 0, stream>>>(f_sum, conv_w[2], conv_b[2], cnt_g, out_f);
  fc_layer< 128,1024, 128, 0, 0, 1><<<256, 256, 0, stream>>>(out_f, fc_w[0], fc_b[0], nullptr, Y1);
  fc_layer<1024, 512, 256, 1, 0, 4><<<512, 256, 0, stream>>>(Y1, fc_w[1], fc_b[1], nullptr, Y2);
  fc_layer< 512, 256, 128, 1, 0, 4><<<256, 256, 0, stream>>>(Y2, fc_w[2], fc_b[2], nullptr, Y3);
  fc_layer< 256, 128,  32, 1, 0, 8><<<256, 256, 0, stream>>>(Y3, fc_w[3], fc_b[3], nullptr, Y4);
  fc_layer< 128,  10, 128, 1, 0, 1><<< 16, 256, 0, stream>>>(Y4, fc_w[4], fc_b[4], nullptr, out_y);
}